// Round 26
// baseline (371.986 us; speedup 1.0000x reference)
//
#include <hip/hip_runtime.h>
#include <math.h>

#define N_NODES  50000
#define N_EDGES  800000
#define HIDDEN   128
#define N_LAYERS 3
#define N_MASKED 25000
#define N_GRAPHS 64
#define XSLICE   6250              // N_NODES / 8 XCD slices
#define NGRP     32                // edge groups
#define CPG      (N_EDGES / NGRP)  // 25000 edges per group

typedef __attribute__((ext_vector_type(8))) short bf16x8;
typedef __attribute__((ext_vector_type(4))) float f32x4;
typedef __attribute__((ext_vector_type(4))) int   intv4;
typedef __attribute__((ext_vector_type(4))) float floatv4;
typedef __attribute__((ext_vector_type(4))) unsigned uintv4;

#define GLOAD_LDS16(g, l) \
    __builtin_amdgcn_global_load_lds((const __attribute__((address_space(1))) void*)(g), \
                                     (__attribute__((address_space(3))) void*)(l), 16, 0, 0)

// ordered float<->uint mapping (monotonic): preserves IEEE total order
__device__ __forceinline__ unsigned fmap(float f) {
    unsigned u = __float_as_uint(f);
    return (u & 0x80000000u) ? ~u : (u | 0x80000000u);
}
__device__ __forceinline__ float funmap(unsigned u) {
    return __uint_as_float((u & 0x80000000u) ? (u & 0x7FFFFFFFu) : ~u);
}

// split f32 -> bf16 hi (RNE) + bf16 lo (RNE of remainder), packed hi | lo<<16
__device__ __forceinline__ unsigned pack_split(float x) {
    unsigned u = __float_as_uint(x);
    unsigned hi = (u + 0x7fffu + ((u >> 16) & 1u)) >> 16;
    float rem = x - __uint_as_float(hi << 16);
    unsigned v = __float_as_uint(rem);
    unsigned lo = (v + 0x7fffu + ((v >> 16) & 1u)) >> 16;
    return hi | (lo << 16);
}

// ---------------- phase 1: LDS-histogram count | gmax | wprep | xpack ----------------
__global__ void build_kernel(const int* __restrict__ dst, unsigned* __restrict__ partial,
                             unsigned* __restrict__ gmax, const float* __restrict__ W,
                             unsigned short* __restrict__ Whi, unsigned short* __restrict__ Wlo,
                             const float* __restrict__ x, unsigned* __restrict__ xp) {
    const int b = blockIdx.x;
    const int tid = threadIdx.x;
    if (b < 256) {
        __shared__ unsigned hist[XSLICE];   // 25 KB
        const int xcd = b & 7;
        const int g = b >> 3;
        const int lo = xcd * XSLICE;
        for (int i = tid; i < XSLICE; i += 256) hist[i] = 0u;
        __syncthreads();
        const int base = g * CPG;
        for (int e = base + tid * 4; e + 4 <= base + CPG; e += 1024) {
            intv4 d4 = __builtin_nontemporal_load((const intv4*)(dst + e));
            unsigned a = (unsigned)(d4.x - lo), bq = (unsigned)(d4.y - lo);
            unsigned c = (unsigned)(d4.z - lo), d = (unsigned)(d4.w - lo);
            if (a < XSLICE) atomicAdd(&hist[a], 1u);
            if (bq < XSLICE) atomicAdd(&hist[bq], 1u);
            if (c < XSLICE) atomicAdd(&hist[c], 1u);
            if (d < XSLICE) atomicAdd(&hist[d], 1u);
        }
        __syncthreads();
        for (int i = tid; i < XSLICE; i += 256)
            __builtin_nontemporal_store(hist[i], &partial[(size_t)g * N_NODES + lo + i]);
    } else if (b < 288) {
        int i = (b - 256) * 256 + tid;
        if (i < N_GRAPHS * 128) gmax[i] = 0x007FFFFFu;
    } else if (b < 480) {
        int idx = (b - 288) * 256 + tid;
        if (idx < 3 * 16384) {
            int j     = idx & 7;
            int lane  = (idx >> 3) & 63;
            int ct    = (idx >> 9) & 7;
            int ks    = (idx >> 12) & 3;
            int layer = idx >> 14;
            int k = ks * 32 + (lane >> 4) * 8 + j;
            int n = ct * 16 + (lane & 15);
            unsigned p = pack_split(W[layer * 16384 + k * 128 + n]);
            Whi[idx] = (unsigned short)(p & 0xffffu);
            Wlo[idx] = (unsigned short)(p >> 16);
        }
    } else {
        int i0 = (b - 480) * 1024 + tid * 4;   // N*H = 6250*1024 exactly
        floatv4 v = __builtin_nontemporal_load((const floatv4*)(x + i0));
        uintv4 pk;
        pk.x = pack_split(v.x); pk.y = pack_split(v.y);
        pk.z = pack_split(v.z); pk.w = pack_split(v.w);
        __builtin_nontemporal_store(pk, (uintv4*)(xp + i0));
    }
}

// ---------------- scan: sum 32 partials -> deg, per-block inclusive scan ----------------
__global__ void scan_block_kernel(const unsigned* __restrict__ partial,
                                  unsigned* __restrict__ deg,
                                  unsigned* __restrict__ incl, unsigned* __restrict__ bsum) {
    __shared__ unsigned s[1024];
    int i = blockIdx.x * 1024 + threadIdx.x;
    unsigned v = 0u;
    if (i < N_NODES) {
        #pragma unroll 8
        for (int g = 0; g < NGRP; ++g)
            v += __builtin_nontemporal_load(&partial[(size_t)g * N_NODES + i]);
        deg[i] = v;
    }
    s[threadIdx.x] = v;
    __syncthreads();
    for (int off = 1; off < 1024; off <<= 1) {
        unsigned t = (threadIdx.x >= off) ? s[threadIdx.x - off] : 0u;
        __syncthreads();
        s[threadIdx.x] += t;
        __syncthreads();
    }
    if (i < N_NODES) incl[i] = s[threadIdx.x];
    if (threadIdx.x == 1023) bsum[blockIdx.x] = s[1023];
}

// 1-wave shuffle scan over <=64 block sums
__global__ void scan_bsum_kernel(unsigned* __restrict__ bsum, int n) {
    int lane = threadIdx.x;   // 64 threads
    unsigned v = (lane < n) ? bsum[lane] : 0u;
    #pragma unroll
    for (int off = 1; off < 64; off <<= 1) {
        unsigned t = __shfl_up(v, off);
        if (lane >= off) v += t;
    }
    unsigned ex = __shfl_up(v, 1);
    if (lane == 0) ex = 0u;
    if (lane < n) bsum[lane] = ex;
}

// finalize: row_ptr + dinv + convert partial (in-place) to per-(group,node) start offset
__global__ void scan_finalize_kernel(const unsigned* __restrict__ incl,
                                     const unsigned* __restrict__ bsum_ex,
                                     const unsigned* __restrict__ deg,
                                     unsigned* __restrict__ row_ptr,
                                     unsigned* __restrict__ partial,
                                     float* __restrict__ dinv) {
    int i = blockIdx.x * blockDim.x + threadIdx.x;
    if (i > N_NODES) return;
    unsigned v = (i == 0) ? 0u : incl[i - 1] + bsum_ex[(i - 1) >> 10];
    row_ptr[i] = v;
    if (i < N_NODES) {
        dinv[i] = rsqrtf((float)(deg[i] + 1u));   // +1 self-loop
        unsigned running = v;
        #pragma unroll 4
        for (int g = 0; g < NGRP; ++g) {
            unsigned cnt = partial[(size_t)g * N_NODES + i];
            partial[(size_t)g * N_NODES + i] = running;   // read-then-write, in place
            running += cnt;
        }
    }
}

// ---------------- phase 2: fill via LDS cursors (no global atomics) ----------------
__global__ void fill_csr_kernel(const int* __restrict__ src, const int* __restrict__ dst,
                                const unsigned* __restrict__ start,
                                int* __restrict__ csr_src) {
    __shared__ unsigned cur[XSLICE];   // 25 KB
    const int b = blockIdx.x;
    const int tid = threadIdx.x;
    const int xcd = b & 7;
    const int g = b >> 3;
    const int lo = xcd * XSLICE;
    for (int i = tid; i < XSLICE; i += 256)
        cur[i] = start[(size_t)g * N_NODES + lo + i];
    __syncthreads();
    const int base = g * CPG;
    for (int e = base + tid * 4; e + 4 <= base + CPG; e += 1024) {
        intv4 d4 = __builtin_nontemporal_load((const intv4*)(dst + e));
        intv4 s4 = __builtin_nontemporal_load((const intv4*)(src + e));
        unsigned a = (unsigned)(d4.x - lo), bq = (unsigned)(d4.y - lo);
        unsigned c = (unsigned)(d4.z - lo), d = (unsigned)(d4.w - lo);
        if (a < XSLICE) __builtin_nontemporal_store(s4.x, &csr_src[atomicAdd(&cur[a], 1u)]);
        if (bq < XSLICE) __builtin_nontemporal_store(s4.y, &csr_src[atomicAdd(&cur[bq], 1u)]);
        if (c < XSLICE) __builtin_nontemporal_store(s4.z, &csr_src[atomicAdd(&cur[c], 1u)]);
        if (d < XSLICE) __builtin_nontemporal_store(s4.w, &csr_src[atomicAdd(&cur[d], 1u)]);
    }
}

// ---------------- MFMA GEMM v6 (NT output stores) ----------------
template<int MODE>
__global__ __launch_bounds__(512, 1) void mfma_gemm_kernel(const unsigned* __restrict__ Ap,
                                                           const unsigned short* __restrict__ Wh,
                                                           const unsigned short* __restrict__ Wl,
                                                           const float* __restrict__ dinv,
                                                           const float* __restrict__ bias,
                                                           const int* __restrict__ batch,
                                                           unsigned* __restrict__ gmax,
                                                           float* __restrict__ Out,
                                                           int nrows) {
    extern __shared__ char smem[];
    unsigned short* WhL = (unsigned short*)smem;            // 32 KB
    unsigned short* WlL = (unsigned short*)(smem + 32768);  // 32 KB
    uint4* AL4 = (uint4*)(smem + 65536);                    // 64 KB
    const int tid = threadIdx.x;
    const int lane = tid & 63;
    const int w = tid >> 6;

    #pragma unroll
    for (int i = 0; i < 4; ++i) {
        int m = tid + i * 512;
        GLOAD_LDS16((const char*)Wh + (size_t)m * 16, smem + (size_t)m * 16);
        GLOAD_LDS16((const char*)Wl + (size_t)m * 16, smem + 32768 + (size_t)m * 16);
    }

    const int ntiles = (nrows + 127) >> 7;
    const int rloc = w * 16 + (lane & 15);
    const int rx = rloc & 7;
    const int colBase = lane & 15;
    const int rgrp = lane >> 4;

    for (int t = blockIdx.x; t < ntiles; t += gridDim.x) {
        const int tileBase = t * 128;
        __syncthreads();

        #pragma unroll
        for (int i = 0; i < 8; ++i) {
            int n = tid + i * 512;
            int r = n >> 5;
            int c = n & 31;
            int grow = tileBase + r;
            if (grow > nrows - 1) grow = nrows - 1;
            GLOAD_LDS16(Ap + (size_t)grow * 128 + ((c ^ (r & 7)) << 2),
                        smem + 65536 + (size_t)n * 16);
        }
        __syncthreads();

        f32x4 acc[8];
        #pragma unroll
        for (int c = 0; c < 8; ++c) acc[c] = (f32x4){0.f, 0.f, 0.f, 0.f};

        #pragma unroll
        for (int ks = 0; ks < 4; ++ks) {
            int c0 = ks * 8 + (lane >> 4) * 2;
            uint4 a0 = AL4[rloc * 32 + (c0 ^ rx)];
            uint4 a1 = AL4[rloc * 32 + ((c0 + 1) ^ rx)];
            unsigned pv[8] = {a0.x, a0.y, a0.z, a0.w, a1.x, a1.y, a1.z, a1.w};
            bf16x8 ah, al;
            #pragma unroll
            for (int j = 0; j < 8; ++j) {
                ah[j] = (short)(pv[j] & 0xffffu);
                al[j] = (short)(pv[j] >> 16);
            }
            const unsigned short* wbh = WhL + ks * 4096 + lane * 8;
            const unsigned short* wbl = WlL + ks * 4096 + lane * 8;
            #pragma unroll
            for (int ct = 0; ct < 8; ++ct) {
                bf16x8 bh = *(const bf16x8*)(wbh + ct * 512);
                bf16x8 bl = *(const bf16x8*)(wbl + ct * 512);
                acc[ct] = __builtin_amdgcn_mfma_f32_16x16x32_bf16(ah, bh, acc[ct], 0, 0, 0);
                acc[ct] = __builtin_amdgcn_mfma_f32_16x16x32_bf16(al, bh, acc[ct], 0, 0, 0);
                acc[ct] = __builtin_amdgcn_mfma_f32_16x16x32_bf16(ah, bl, acc[ct], 0, 0, 0);
            }
        }

        // C/D layout: col = lane&15, row = (lane>>4)*4 + reg   [m89-verified]
        #pragma unroll
        for (int r = 0; r < 4; ++r) {
            int row = tileBase + w * 16 + rgrp * 4 + r;
            if (row >= nrows) continue;
            float d = 0.f;
            int bofs = 0;
            if (MODE == 0 || MODE == 1) d = dinv[row];
            if (MODE == 2) bofs = batch[row] * 128;
            #pragma unroll
            for (int ct = 0; ct < 8; ++ct) {
                int col = ct * 16 + colBase;
                float o = acc[ct][r];
                if (MODE == 0) {
                    __builtin_nontemporal_store(o * d, &Out[(size_t)row * 128 + col]);
                } else {
                    o += bias[col];
                    o = o > 0.f ? o : expm1f(o);
                    if (MODE == 1)
                        __builtin_nontemporal_store(o * d, &Out[(size_t)row * 128 + col]);
                    else
                        atomicMax(&gmax[bofs + col], fmap(o));
                }
            }
        }
    }
}

// ---------------- CSR gather (r5 shape) — NT idx loads + NT output stores ----------
template<int GMODE>
__global__ __launch_bounds__(256) void gather_kernel(const float* __restrict__ tab,
                                                     const unsigned* __restrict__ row_ptr,
                                                     const int* __restrict__ csr_src,
                                                     const float* __restrict__ dinv,
                                                     const float* __restrict__ bias,
                                                     float* __restrict__ outf,
                                                     unsigned* __restrict__ outp,
                                                     const int* __restrict__ nodes,
                                                     int n_items) {
    int wid = (blockIdx.x * blockDim.x + threadIdx.x) >> 6;
    int w = wid >> 1;
    if (w >= n_items) return;
    const int f = ((wid & 1) << 6) | (threadIdx.x & 63);
    const int v = nodes ? nodes[w] : w;

    const unsigned s0 = row_ptr[v], e0 = row_ptr[v + 1];
    const float* __restrict__ base = tab + f;

    float acc[8];
    #pragma unroll
    for (int j = 0; j < 8; ++j) acc[j] = 0.f;
    acc[0] = base[(size_t)v << 7];   // self-loop row

    unsigned i = s0;
    if (i + 8 <= e0) {
        int idx[8];
        #pragma unroll
        for (int j = 0; j < 8; ++j) idx[j] = __builtin_nontemporal_load(&csr_src[i + j]);
        for (; i + 16 <= e0; i += 8) {
            int nxt[8];
            #pragma unroll
            for (int j = 0; j < 8; ++j)
                nxt[j] = __builtin_nontemporal_load(&csr_src[i + 8 + j]);
            #pragma unroll
            for (int j = 0; j < 8; ++j) acc[j] += base[(size_t)idx[j] << 7];
            #pragma unroll
            for (int j = 0; j < 8; ++j) idx[j] = nxt[j];
        }
        #pragma unroll
        for (int j = 0; j < 8; ++j) acc[j] += base[(size_t)idx[j] << 7];
        i += 8;
    }
    if (i + 4 <= e0) {
        #pragma unroll
        for (int j = 0; j < 4; ++j)
            acc[j] += base[(size_t)__builtin_nontemporal_load(&csr_src[i + j]) << 7];
        i += 4;
    }
    for (; i < e0; ++i)
        acc[0] += base[(size_t)__builtin_nontemporal_load(&csr_src[i]) << 7];

    float dv = dinv[v];
    float sumall = ((acc[0] + acc[1]) + (acc[2] + acc[3])) +
                   ((acc[4] + acc[5]) + (acc[6] + acc[7]));
    if (GMODE == 0) {
        float o = dv * sumall + bias[f];
        o = o > 0.f ? o : expm1f(o);
        __builtin_nontemporal_store(o * dv, &outf[((size_t)w << 7) + f]);
    } else {
        __builtin_nontemporal_store(pack_split(dv * sumall), &outp[((size_t)w << 7) + f]);
    }
}

// ---------------- finish: out[g] = sum_f unmap(gmax[g][f]) * w[f] + b ----------------
__global__ void pool_finish_kernel(const unsigned* __restrict__ gmax,
                                   const float* __restrict__ w, const float* __restrict__ b,
                                   float* __restrict__ out) {
    const int g = blockIdx.x;
    const int f = threadIdx.x;
    float val = funmap(gmax[g * 128 + f]) * w[f];
    #pragma unroll
    for (int off = 32; off > 0; off >>= 1) val += __shfl_down(val, off);
    __shared__ float ps[2];
    if ((threadIdx.x & 63) == 0) ps[threadIdx.x >> 6] = val;
    __syncthreads();
    if (threadIdx.x == 0) out[g] = ps[0] + ps[1] + b[0];
}

extern "C" void kernel_launch(void* const* d_in, const int* in_sizes, int n_in,
                              void* d_out, int out_size, void* d_ws, size_t ws_size,
                              hipStream_t stream) {
    const float* x      = (const float*)d_in[0];
    const int*   ei     = (const int*)d_in[1];
    const int*   mask   = (const int*)d_in[2];
    const int*   batch  = (const int*)d_in[3];
    const float* conv_w = (const float*)d_in[4];
    const float* conv_b = (const float*)d_in[5];
    const float* lt1_w  = (const float*)d_in[6];
    const float* lt1_b  = (const float*)d_in[7];
    float* out = (float*)d_out;

    const int* e_src = ei;
    const int* e_dst = ei + N_EDGES;

    // ---- workspace carve-up (aligned to 256B) ----
    char* ws = (char*)d_ws;
    auto carve = [&](size_t bytes) { char* p = ws; ws += (bytes + 255) & ~(size_t)255; return p; };
    unsigned* deg     = (unsigned*)carve(N_NODES * 4);
    float*    dinv    = (float*)   carve(N_NODES * 4);
    unsigned* row_ptr = (unsigned*)carve((N_NODES + 1) * 4);
    unsigned* partial = (unsigned*)carve((size_t)NGRP * N_NODES * 4);   // 6.4 MB
    unsigned* bsum    = (unsigned*)carve(64 * 4);
    unsigned* gmax    = (unsigned*)carve(N_GRAPHS * 128 * 4);
    unsigned short* wph = (unsigned short*)carve(3 * 16384 * 2);
    unsigned short* wpl = (unsigned short*)carve(3 * 16384 * 2);
    int*      csr_src = (int*)     carve((size_t)N_EDGES * 4);
    unsigned* xp      = (unsigned*)carve((size_t)N_NODES * HIDDEN * 4);
    char*     reg1    = carve((size_t)N_NODES * HIDDEN * 4);
    char*     reg2    = carve((size_t)N_NODES * HIDDEN * 4);
    unsigned* incl    = (unsigned*)csr_src;  // alias: dead before fill_csr runs

    float*    bufB  = (float*)reg1;
    float*    bufB2 = (float*)reg1;
    float*    bufA  = (float*)reg2;
    unsigned* bufAp = (unsigned*)reg2;
    unsigned* bufCp = (unsigned*)reg2;

    const int NB_SCAN = (N_NODES + 1023) / 1024;  // 49
    const int XPACK_BLOCKS = N_NODES * HIDDEN / 1024;   // 6250

    // ---- build: LDS-histogram counting sort (no global atomics) ----
    build_kernel<<<480 + XPACK_BLOCKS, 256, 0, stream>>>(e_dst, partial, gmax, conv_w,
                                                         wph, wpl, x, xp);
    scan_block_kernel<<<NB_SCAN, 1024, 0, stream>>>(partial, deg, incl, bsum);
    scan_bsum_kernel<<<1, 64, 0, stream>>>(bsum, NB_SCAN);
    scan_finalize_kernel<<<(N_NODES + 256) / 256, 256, 0, stream>>>(incl, bsum, deg,
                                                                    row_ptr, partial, dinv);
    fill_csr_kernel<<<256, 256, 0, stream>>>(e_src, e_dst, partial, csr_src);

    const size_t LDS_BYTES = 131072;
    auto gemm_grid = [](int rows) { int t = (rows + 127) / 128; return t < 256 ? t : 256; };
    auto ga_blocks = [](int items) { return (items * 2 * 64 + 255) / 256; };

    // L1: bufA = dinv*(x@W1)
    mfma_gemm_kernel<0><<<gemm_grid(N_NODES), 512, LDS_BYTES, stream>>>(
        xp, wph, wpl, dinv, nullptr, nullptr, nullptr, bufA, N_NODES);
    // bufB = dinv*ELU(dinv*Agg(bufA) + b1)
    gather_kernel<0><<<ga_blocks(N_NODES), 256, 0, stream>>>(
        bufA, row_ptr, csr_src, dinv, conv_b, bufB, nullptr, nullptr, N_NODES);
    // L2 gather-first: bufAp = pack(Agg(bufB))
    gather_kernel<1><<<ga_blocks(N_NODES), 256, 0, stream>>>(
        bufB, row_ptr, csr_src, dinv, nullptr, nullptr, bufAp, nullptr, N_NODES);
    // bufB2 = dinv*ELU(bufAp@W2 + b2)
    mfma_gemm_kernel<1><<<gemm_grid(N_NODES), 512, LDS_BYTES, stream>>>(
        bufAp, wph + 16384, wpl + 16384, dinv, conv_b + HIDDEN, nullptr, nullptr,
        bufB2, N_NODES);
    // L3 gather-first masked: bufCp = pack(Agg_mask(bufB2))
    gather_kernel<1><<<ga_blocks(N_MASKED), 256, 0, stream>>>(
        bufB2, row_ptr, csr_src, dinv, nullptr, nullptr, bufCp, mask, N_MASKED);
    // pool(ELU(bufCp@W3 + b3)) via atomicMax
    mfma_gemm_kernel<2><<<gemm_grid(N_MASKED), 512, LDS_BYTES, stream>>>(
        bufCp, wph + 32768, wpl + 32768, nullptr, conv_b + 2 * HIDDEN, batch, gmax,
        nullptr, N_MASKED);

    pool_finish_kernel<<<N_GRAPHS, HIDDEN, 0, stream>>>(gmax, lt1_w, lt1_b, out);
}

// Round 27
// 318.470 us; speedup vs baseline: 1.1680x; 1.1680x over previous
//
#include <hip/hip_runtime.h>
#include <math.h>

#define N_NODES  50000
#define N_EDGES  800000
#define HIDDEN   128
#define N_LAYERS 3
#define N_MASKED 25000
#define N_GRAPHS 64
#define XSLICE   6250              // N_NODES / 8 XCD slices
#define NGRP     32                // edge groups
#define CPG      (N_EDGES / NGRP)  // 25000 edges per group

typedef __attribute__((ext_vector_type(8))) short bf16x8;
typedef __attribute__((ext_vector_type(4))) float f32x4;

#define GLOAD_LDS16(g, l) \
    __builtin_amdgcn_global_load_lds((const __attribute__((address_space(1))) void*)(g), \
                                     (__attribute__((address_space(3))) void*)(l), 16, 0, 0)

// ordered float<->uint mapping (monotonic): preserves IEEE total order
__device__ __forceinline__ unsigned fmap(float f) {
    unsigned u = __float_as_uint(f);
    return (u & 0x80000000u) ? ~u : (u | 0x80000000u);
}
__device__ __forceinline__ float funmap(unsigned u) {
    return __uint_as_float((u & 0x80000000u) ? (u & 0x7FFFFFFFu) : ~u);
}

// split f32 -> bf16 hi (RNE) + bf16 lo (RNE of remainder), packed hi | lo<<16
__device__ __forceinline__ unsigned pack_split(float x) {
    unsigned u = __float_as_uint(x);
    unsigned hi = (u + 0x7fffu + ((u >> 16) & 1u)) >> 16;
    float rem = x - __uint_as_float(hi << 16);
    unsigned v = __float_as_uint(rem);
    unsigned lo = (v + 0x7fffu + ((v >> 16) & 1u)) >> 16;
    return hi | (lo << 16);
}

// ---------------- phase 1: LDS-histogram count | gmax | wprep | xpack ----------------
__global__ void build_kernel(const int* __restrict__ dst, unsigned* __restrict__ partial,
                             unsigned* __restrict__ gmax, const float* __restrict__ W,
                             unsigned short* __restrict__ Whi, unsigned short* __restrict__ Wlo,
                             const float* __restrict__ x, unsigned* __restrict__ xp) {
    const int b = blockIdx.x;
    const int tid = threadIdx.x;
    if (b < 256) {
        __shared__ unsigned hist[XSLICE];   // 25 KB
        const int xcd = b & 7;
        const int g = b >> 3;
        const int lo = xcd * XSLICE;
        for (int i = tid; i < XSLICE; i += 256) hist[i] = 0u;
        __syncthreads();
        const int base = g * CPG;
        for (int e = base + tid * 4; e + 4 <= base + CPG; e += 1024) {
            int4 d4 = *(const int4*)(dst + e);
            unsigned a = (unsigned)(d4.x - lo), bq = (unsigned)(d4.y - lo);
            unsigned c = (unsigned)(d4.z - lo), d = (unsigned)(d4.w - lo);
            if (a < XSLICE) atomicAdd(&hist[a], 1u);
            if (bq < XSLICE) atomicAdd(&hist[bq], 1u);
            if (c < XSLICE) atomicAdd(&hist[c], 1u);
            if (d < XSLICE) atomicAdd(&hist[d], 1u);
        }
        __syncthreads();
        for (int i = tid; i < XSLICE; i += 256)
            partial[(size_t)g * N_NODES + lo + i] = hist[i];
    } else if (b < 288) {
        int i = (b - 256) * 256 + tid;
        if (i < N_GRAPHS * 128) gmax[i] = 0x007FFFFFu;
    } else if (b < 480) {
        int idx = (b - 288) * 256 + tid;
        if (idx < 3 * 16384) {
            int j     = idx & 7;
            int lane  = (idx >> 3) & 63;
            int ct    = (idx >> 9) & 7;
            int ks    = (idx >> 12) & 3;
            int layer = idx >> 14;
            int k = ks * 32 + (lane >> 4) * 8 + j;
            int n = ct * 16 + (lane & 15);
            unsigned p = pack_split(W[layer * 16384 + k * 128 + n]);
            Whi[idx] = (unsigned short)(p & 0xffffu);
            Wlo[idx] = (unsigned short)(p >> 16);
        }
    } else {
        int i0 = (b - 480) * 1024 + tid * 4;   // N*H = 6250*1024 exactly
        float4 v = *(const float4*)(x + i0);
        uint4 pk = make_uint4(pack_split(v.x), pack_split(v.y),
                              pack_split(v.z), pack_split(v.w));
        *(uint4*)(xp + i0) = pk;
    }
}

// ---------------- scan: sum 32 partials -> deg, per-block inclusive scan ----------------
__global__ void scan_block_kernel(const unsigned* __restrict__ partial,
                                  unsigned* __restrict__ deg,
                                  unsigned* __restrict__ incl, unsigned* __restrict__ bsum) {
    __shared__ unsigned s[1024];
    int i = blockIdx.x * 1024 + threadIdx.x;
    unsigned v = 0u;
    if (i < N_NODES) {
        #pragma unroll 8
        for (int g = 0; g < NGRP; ++g) v += partial[(size_t)g * N_NODES + i];
        deg[i] = v;
    }
    s[threadIdx.x] = v;
    __syncthreads();
    for (int off = 1; off < 1024; off <<= 1) {
        unsigned t = (threadIdx.x >= off) ? s[threadIdx.x - off] : 0u;
        __syncthreads();
        s[threadIdx.x] += t;
        __syncthreads();
    }
    if (i < N_NODES) incl[i] = s[threadIdx.x];
    if (threadIdx.x == 1023) bsum[blockIdx.x] = s[1023];
}

// 1-wave shuffle scan over <=64 block sums
__global__ void scan_bsum_kernel(unsigned* __restrict__ bsum, int n) {
    int lane = threadIdx.x;   // 64 threads
    unsigned v = (lane < n) ? bsum[lane] : 0u;
    #pragma unroll
    for (int off = 1; off < 64; off <<= 1) {
        unsigned t = __shfl_up(v, off);
        if (lane >= off) v += t;
    }
    unsigned ex = __shfl_up(v, 1);
    if (lane == 0) ex = 0u;
    if (lane < n) bsum[lane] = ex;
}

// finalize: row_ptr + dinv + convert partial (in-place) to per-(group,node) start offset
__global__ void scan_finalize_kernel(const unsigned* __restrict__ incl,
                                     const unsigned* __restrict__ bsum_ex,
                                     const unsigned* __restrict__ deg,
                                     unsigned* __restrict__ row_ptr,
                                     unsigned* __restrict__ partial,
                                     float* __restrict__ dinv) {
    int i = blockIdx.x * blockDim.x + threadIdx.x;
    if (i > N_NODES) return;
    unsigned v = (i == 0) ? 0u : incl[i - 1] + bsum_ex[(i - 1) >> 10];
    row_ptr[i] = v;
    if (i < N_NODES) {
        dinv[i] = rsqrtf((float)(deg[i] + 1u));   // +1 self-loop
        unsigned running = v;
        #pragma unroll 4
        for (int g = 0; g < NGRP; ++g) {
            unsigned cnt = partial[(size_t)g * N_NODES + i];
            partial[(size_t)g * N_NODES + i] = running;   // read-then-write, in place
            running += cnt;
        }
    }
}

// ---------------- phase 2: fill via LDS cursors (no global atomics) ----------------
__global__ void fill_csr_kernel(const int* __restrict__ src, const int* __restrict__ dst,
                                const unsigned* __restrict__ start,
                                int* __restrict__ csr_src) {
    __shared__ unsigned cur[XSLICE];   // 25 KB
    const int b = blockIdx.x;
    const int tid = threadIdx.x;
    const int xcd = b & 7;
    const int g = b >> 3;
    const int lo = xcd * XSLICE;
    for (int i = tid; i < XSLICE; i += 256)
        cur[i] = start[(size_t)g * N_NODES + lo + i];
    __syncthreads();
    const int base = g * CPG;
    for (int e = base + tid * 4; e + 4 <= base + CPG; e += 1024) {
        int4 d4 = *(const int4*)(dst + e);
        int4 s4 = *(const int4*)(src + e);
        unsigned a = (unsigned)(d4.x - lo), bq = (unsigned)(d4.y - lo);
        unsigned c = (unsigned)(d4.z - lo), d = (unsigned)(d4.w - lo);
        if (a < XSLICE) csr_src[atomicAdd(&cur[a], 1u)] = s4.x;
        if (bq < XSLICE) csr_src[atomicAdd(&cur[bq], 1u)] = s4.y;
        if (c < XSLICE) csr_src[atomicAdd(&cur[c], 1u)] = s4.z;
        if (d < XSLICE) csr_src[atomicAdd(&cur[d], 1u)] = s4.w;
    }
}

// ---------------- MFMA GEMM v6 ----------------
template<int MODE>
__global__ __launch_bounds__(512, 1) void mfma_gemm_kernel(const unsigned* __restrict__ Ap,
                                                           const unsigned short* __restrict__ Wh,
                                                           const unsigned short* __restrict__ Wl,
                                                           const float* __restrict__ dinv,
                                                           const float* __restrict__ bias,
                                                           const int* __restrict__ batch,
                                                           unsigned* __restrict__ gmax,
                                                           float* __restrict__ Out,
                                                           int nrows) {
    extern __shared__ char smem[];
    unsigned short* WhL = (unsigned short*)smem;            // 32 KB
    unsigned short* WlL = (unsigned short*)(smem + 32768);  // 32 KB
    uint4* AL4 = (uint4*)(smem + 65536);                    // 64 KB
    const int tid = threadIdx.x;
    const int lane = tid & 63;
    const int w = tid >> 6;

    #pragma unroll
    for (int i = 0; i < 4; ++i) {
        int m = tid + i * 512;
        GLOAD_LDS16((const char*)Wh + (size_t)m * 16, smem + (size_t)m * 16);
        GLOAD_LDS16((const char*)Wl + (size_t)m * 16, smem + 32768 + (size_t)m * 16);
    }

    const int ntiles = (nrows + 127) >> 7;
    const int rloc = w * 16 + (lane & 15);
    const int rx = rloc & 7;
    const int colBase = lane & 15;
    const int rgrp = lane >> 4;

    for (int t = blockIdx.x; t < ntiles; t += gridDim.x) {
        const int tileBase = t * 128;
        __syncthreads();

        #pragma unroll
        for (int i = 0; i < 8; ++i) {
            int n = tid + i * 512;
            int r = n >> 5;
            int c = n & 31;
            int grow = tileBase + r;
            if (grow > nrows - 1) grow = nrows - 1;
            GLOAD_LDS16(Ap + (size_t)grow * 128 + ((c ^ (r & 7)) << 2),
                        smem + 65536 + (size_t)n * 16);
        }
        __syncthreads();

        f32x4 acc[8];
        #pragma unroll
        for (int c = 0; c < 8; ++c) acc[c] = (f32x4){0.f, 0.f, 0.f, 0.f};

        #pragma unroll
        for (int ks = 0; ks < 4; ++ks) {
            int c0 = ks * 8 + (lane >> 4) * 2;
            uint4 a0 = AL4[rloc * 32 + (c0 ^ rx)];
            uint4 a1 = AL4[rloc * 32 + ((c0 + 1) ^ rx)];
            unsigned pv[8] = {a0.x, a0.y, a0.z, a0.w, a1.x, a1.y, a1.z, a1.w};
            bf16x8 ah, al;
            #pragma unroll
            for (int j = 0; j < 8; ++j) {
                ah[j] = (short)(pv[j] & 0xffffu);
                al[j] = (short)(pv[j] >> 16);
            }
            const unsigned short* wbh = WhL + ks * 4096 + lane * 8;
            const unsigned short* wbl = WlL + ks * 4096 + lane * 8;
            #pragma unroll
            for (int ct = 0; ct < 8; ++ct) {
                bf16x8 bh = *(const bf16x8*)(wbh + ct * 512);
                bf16x8 bl = *(const bf16x8*)(wbl + ct * 512);
                acc[ct] = __builtin_amdgcn_mfma_f32_16x16x32_bf16(ah, bh, acc[ct], 0, 0, 0);
                acc[ct] = __builtin_amdgcn_mfma_f32_16x16x32_bf16(al, bh, acc[ct], 0, 0, 0);
                acc[ct] = __builtin_amdgcn_mfma_f32_16x16x32_bf16(ah, bl, acc[ct], 0, 0, 0);
            }
        }

        // C/D layout: col = lane&15, row = (lane>>4)*4 + reg   [m89-verified]
        #pragma unroll
        for (int r = 0; r < 4; ++r) {
            int row = tileBase + w * 16 + rgrp * 4 + r;
            if (row >= nrows) continue;
            float d = 0.f;
            int bofs = 0;
            if (MODE == 0 || MODE == 1) d = dinv[row];
            if (MODE == 2) bofs = batch[row] * 128;
            #pragma unroll
            for (int ct = 0; ct < 8; ++ct) {
                int col = ct * 16 + colBase;
                float o = acc[ct][r];
                if (MODE == 0) {
                    Out[(size_t)row * 128 + col] = o * d;
                } else {
                    o += bias[col];
                    o = o > 0.f ? o : expm1f(o);
                    if (MODE == 1) Out[(size_t)row * 128 + col] = o * d;
                    else           atomicMax(&gmax[bofs + col], fmap(o));
                }
            }
        }
    }
}

// ---------------- CSR gather (r5 shape) ----------------
template<int GMODE>
__global__ __launch_bounds__(256) void gather_kernel(const float* __restrict__ tab,
                                                     const unsigned* __restrict__ row_ptr,
                                                     const int* __restrict__ csr_src,
                                                     const float* __restrict__ dinv,
                                                     const float* __restrict__ bias,
                                                     float* __restrict__ outf,
                                                     unsigned* __restrict__ outp,
                                                     const int* __restrict__ nodes,
                                                     int n_items) {
    int wid = (blockIdx.x * blockDim.x + threadIdx.x) >> 6;
    int w = wid >> 1;
    if (w >= n_items) return;
    const int f = ((wid & 1) << 6) | (threadIdx.x & 63);
    const int v = nodes ? nodes[w] : w;

    const unsigned s0 = row_ptr[v], e0 = row_ptr[v + 1];
    const float* __restrict__ base = tab + f;

    float acc[8];
    #pragma unroll
    for (int j = 0; j < 8; ++j) acc[j] = 0.f;
    acc[0] = base[(size_t)v << 7];   // self-loop row

    unsigned i = s0;
    if (i + 8 <= e0) {
        int idx[8];
        #pragma unroll
        for (int j = 0; j < 8; ++j) idx[j] = csr_src[i + j];
        for (; i + 16 <= e0; i += 8) {
            int nxt[8];
            #pragma unroll
            for (int j = 0; j < 8; ++j) nxt[j] = csr_src[i + 8 + j];
            #pragma unroll
            for (int j = 0; j < 8; ++j) acc[j] += base[(size_t)idx[j] << 7];
            #pragma unroll
            for (int j = 0; j < 8; ++j) idx[j] = nxt[j];
        }
        #pragma unroll
        for (int j = 0; j < 8; ++j) acc[j] += base[(size_t)idx[j] << 7];
        i += 8;
    }
    if (i + 4 <= e0) {
        #pragma unroll
        for (int j = 0; j < 4; ++j) acc[j] += base[(size_t)csr_src[i + j] << 7];
        i += 4;
    }
    for (; i < e0; ++i) acc[0] += base[(size_t)csr_src[i] << 7];

    float dv = dinv[v];
    float sumall = ((acc[0] + acc[1]) + (acc[2] + acc[3])) +
                   ((acc[4] + acc[5]) + (acc[6] + acc[7]));
    if (GMODE == 0) {
        float o = dv * sumall + bias[f];
        o = o > 0.f ? o : expm1f(o);
        outf[((size_t)w << 7) + f] = o * dv;   // pre-scale for next aggregation
    } else {
        outp[((size_t)w << 7) + f] = pack_split(dv * sumall);
    }
}

// ---------------- finish: out[g] = sum_f unmap(gmax[g][f]) * w[f] + b ----------------
__global__ void pool_finish_kernel(const unsigned* __restrict__ gmax,
                                   const float* __restrict__ w, const float* __restrict__ b,
                                   float* __restrict__ out) {
    const int g = blockIdx.x;
    const int f = threadIdx.x;
    float val = funmap(gmax[g * 128 + f]) * w[f];
    #pragma unroll
    for (int off = 32; off > 0; off >>= 1) val += __shfl_down(val, off);
    __shared__ float ps[2];
    if ((threadIdx.x & 63) == 0) ps[threadIdx.x >> 6] = val;
    __syncthreads();
    if (threadIdx.x == 0) out[g] = ps[0] + ps[1] + b[0];
}

extern "C" void kernel_launch(void* const* d_in, const int* in_sizes, int n_in,
                              void* d_out, int out_size, void* d_ws, size_t ws_size,
                              hipStream_t stream) {
    const float* x      = (const float*)d_in[0];
    const int*   ei     = (const int*)d_in[1];
    const int*   mask   = (const int*)d_in[2];
    const int*   batch  = (const int*)d_in[3];
    const float* conv_w = (const float*)d_in[4];
    const float* conv_b = (const float*)d_in[5];
    const float* lt1_w  = (const float*)d_in[6];
    const float* lt1_b  = (const float*)d_in[7];
    float* out = (float*)d_out;

    const int* e_src = ei;
    const int* e_dst = ei + N_EDGES;

    // ---- workspace carve-up (aligned to 256B) ----
    char* ws = (char*)d_ws;
    auto carve = [&](size_t bytes) { char* p = ws; ws += (bytes + 255) & ~(size_t)255; return p; };
    unsigned* deg     = (unsigned*)carve(N_NODES * 4);
    float*    dinv    = (float*)   carve(N_NODES * 4);
    unsigned* row_ptr = (unsigned*)carve((N_NODES + 1) * 4);
    unsigned* partial = (unsigned*)carve((size_t)NGRP * N_NODES * 4);   // 6.4 MB
    unsigned* bsum    = (unsigned*)carve(64 * 4);
    unsigned* gmax    = (unsigned*)carve(N_GRAPHS * 128 * 4);
    unsigned short* wph = (unsigned short*)carve(3 * 16384 * 2);
    unsigned short* wpl = (unsigned short*)carve(3 * 16384 * 2);
    int*      csr_src = (int*)     carve((size_t)N_EDGES * 4);
    unsigned* xp      = (unsigned*)carve((size_t)N_NODES * HIDDEN * 4);
    char*     reg1    = carve((size_t)N_NODES * HIDDEN * 4);
    char*     reg2    = carve((size_t)N_NODES * HIDDEN * 4);
    unsigned* incl    = (unsigned*)csr_src;  // alias: dead before fill_csr runs

    float*    bufB  = (float*)reg1;
    float*    bufB2 = (float*)reg1;
    float*    bufA  = (float*)reg2;
    unsigned* bufAp = (unsigned*)reg2;
    unsigned* bufCp = (unsigned*)reg2;

    const int NB_SCAN = (N_NODES + 1023) / 1024;  // 49
    const int XPACK_BLOCKS = N_NODES * HIDDEN / 1024;   // 6250

    // ---- build: LDS-histogram counting sort (no global atomics) ----
    build_kernel<<<480 + XPACK_BLOCKS, 256, 0, stream>>>(e_dst, partial, gmax, conv_w,
                                                         wph, wpl, x, xp);
    scan_block_kernel<<<NB_SCAN, 1024, 0, stream>>>(partial, deg, incl, bsum);
    scan_bsum_kernel<<<1, 64, 0, stream>>>(bsum, NB_SCAN);
    scan_finalize_kernel<<<(N_NODES + 256) / 256, 256, 0, stream>>>(incl, bsum, deg,
                                                                    row_ptr, partial, dinv);
    fill_csr_kernel<<<256, 256, 0, stream>>>(e_src, e_dst, partial, csr_src);

    const size_t LDS_BYTES = 131072;
    auto gemm_grid = [](int rows) { int t = (rows + 127) / 128; return t < 256 ? t : 256; };
    auto ga_blocks = [](int items) { return (items * 2 * 64 + 255) / 256; };

    // L1: bufA = dinv*(x@W1)
    mfma_gemm_kernel<0><<<gemm_grid(N_NODES), 512, LDS_BYTES, stream>>>(
        xp, wph, wpl, dinv, nullptr, nullptr, nullptr, bufA, N_NODES);
    // bufB = dinv*ELU(dinv*Agg(bufA) + b1)
    gather_kernel<0><<<ga_blocks(N_NODES), 256, 0, stream>>>(
        bufA, row_ptr, csr_src, dinv, conv_b, bufB, nullptr, nullptr, N_NODES);
    // L2 gather-first: bufAp = pack(Agg(bufB))
    gather_kernel<1><<<ga_blocks(N_NODES), 256, 0, stream>>>(
        bufB, row_ptr, csr_src, dinv, nullptr, nullptr, bufAp, nullptr, N_NODES);
    // bufB2 = dinv*ELU(bufAp@W2 + b2)
    mfma_gemm_kernel<1><<<gemm_grid(N_NODES), 512, LDS_BYTES, stream>>>(
        bufAp, wph + 16384, wpl + 16384, dinv, conv_b + HIDDEN, nullptr, nullptr,
        bufB2, N_NODES);
    // L3 gather-first masked: bufCp = pack(Agg_mask(bufB2))
    gather_kernel<1><<<ga_blocks(N_MASKED), 256, 0, stream>>>(
        bufB2, row_ptr, csr_src, dinv, nullptr, nullptr, bufCp, mask, N_MASKED);
    // pool(ELU(bufCp@W3 + b3)) via atomicMax
    mfma_gemm_kernel<2><<<gemm_grid(N_MASKED), 512, LDS_BYTES, stream>>>(
        bufCp, wph + 32768, wpl + 32768, nullptr, conv_b + 2 * HIDDEN, batch, gmax,
        nullptr, N_MASKED);

    pool_finish_kernel<<<N_GRAPHS, HIDDEN, 0, stream>>>(gmax, lt1_w, lt1_b, out);
}